// Round 9
// baseline (395.907 us; speedup 1.0000x reference)
//
#include <hip/hip_runtime.h>
#include <stdint.h>

// ---------------------------------------------------------------------------
// TimeAwareIMULSTMEncoder on MI355X (gfx950) — round 14
// vs round 13 (neutral vmcnt fix -> stall is the serial in-wave chain:
// ds_read -> Whh MFMA chain -> transcendental pointwise, lockstep waves):
//  * X-LOOKAHEAD ACCUMULATOR (in-wave MFMA||VALU overlap): accX[4] holds
//    bias + x(t+1)@Wih, computed with 32 independent MFMAs placed in the
//    same scheduling region as step t's pointwise -> compiler interleaves
//    MFMA issue into transcendental stalls. Step t consumes acc=accX and
//    only runs the 16 recurrence-bound Whh MFMAs on the critical path.
//  * X staged 2 steps ahead: land X(t+2) into Xs[cur] (the buffer X(t)
//    vacated); Ax(t+1) read from Xs[nxt] pre-barrier. Loads issued first
//    in the step -> dep-wait vmcnt(1), store-acks never waited.
//  * Y flush WIDE: h(t-1) flushed from hbuf[cur] as 1 dwordx2/thread
//    (256-B coalesced segments) instead of 4 scattered 2-B stores.
//  * Reg budget: one Bx k-tile in LDS (K=256) -> weights 176 + acc 16 +
//    accX 16 + state ~= 246 < 256. Spill tripwire: WRITE/FETCH growth.
// ---------------------------------------------------------------------------

typedef unsigned short ushort_t;
typedef short short8 __attribute__((ext_vector_type(8)));     // 8 bf16 (4 VGPRs)
typedef float float4v __attribute__((ext_vector_type(4)));    // MFMA acc

#define DEV_INLINE __device__ __forceinline__

DEV_INLINE ushort_t f2bf(float f) {                 // RNE f32 -> bf16 bits
  union { float f; unsigned u; } v; v.f = f;
  unsigned r = v.u + 0x7fffu + ((v.u >> 16) & 1u);
  return (ushort_t)(r >> 16);
}
DEV_INLINE float sigmoidf_(float x) {
  return __builtin_amdgcn_rcpf(1.0f + __expf(-x));
}
DEV_INLINE float tanhf_(float x) {                  // 1 - 2/(1+e^{2x}); safe at +-inf
  return 1.0f - 2.0f * __builtin_amdgcn_rcpf(1.0f + __expf(2.0f * x));
}

// LDS-only barrier: ds-op completion + rendezvous, no vmcnt drain.
DEV_INLINE void lds_barrier() {
  asm volatile("s_waitcnt lgkmcnt(0)\n\ts_barrier" ::: "memory");
}

// async global->LDS, 16B per lane; dst must be wave-uniform base + lane*16.
DEV_INLINE void gload16(const ushort_t* g, ushort_t* l) {
  __builtin_amdgcn_global_load_lds(
      (const __attribute__((address_space(1))) unsigned int*)g,
      (__attribute__((address_space(3))) unsigned int*)l, 16, 0, 0);
}

// --------------------------- weight prep (tiled transpose) ------------------
__global__ __launch_bounds__(256) void k_prep(
    const float* __restrict__ Wih0, const float* __restrict__ Wih1,
    const float* __restrict__ Wih2, const float* __restrict__ Whh0,
    const float* __restrict__ Whh1, const float* __restrict__ Whh2,
    const float* __restrict__ Wout1, const float* __restrict__ Wout2,
    ushort_t* __restrict__ WT)
{
  __shared__ float T[32][65];
  const int b = blockIdx.x;
  const int tid = threadIdx.x;
  const float* S; int Kd, C; size_t dstBase; int kt, nt;
  if (b < 32) {
    int rel = b; int d = (rel >> 3) / 2; kt = (rel >> 3) & 1; nt = rel & 7;
    S = Wih0 + (size_t)d * 64 * 512; C = 512; Kd = 64;
    dstBase = 0 + (size_t)d * 512 * 64;
  } else if (b < 160) {
    int rel = b - 32; int d = (rel >> 3) / 8; kt = (rel >> 3) & 7; nt = rel & 7;
    S = Wih1 + (size_t)d * 256 * 512; C = 512; Kd = 256;
    dstBase = 65536 + (size_t)d * 512 * 256;
  } else if (b < 288) {
    int rel = b - 160; int d = (rel >> 3) / 8; kt = (rel >> 3) & 7; nt = rel & 7;
    S = Wih2 + (size_t)d * 256 * 512; C = 512; Kd = 256;
    dstBase = 327680 + (size_t)d * 512 * 256;
  } else if (b < 352) {
    int rel = b - 288; int d = (rel >> 3) / 4; kt = (rel >> 3) & 3; nt = rel & 7;
    S = Whh0 + (size_t)d * 128 * 512; C = 512; Kd = 128;
    dstBase = 589824 + (size_t)d * 512 * 128;
  } else if (b < 416) {
    int rel = b - 352; int d = (rel >> 3) / 4; kt = (rel >> 3) & 3; nt = rel & 7;
    S = Whh1 + (size_t)d * 128 * 512; C = 512; Kd = 128;
    dstBase = 720896 + (size_t)d * 512 * 128;
  } else if (b < 480) {
    int rel = b - 416; int d = (rel >> 3) / 4; kt = (rel >> 3) & 3; nt = rel & 7;
    S = Whh2 + (size_t)d * 128 * 512; C = 512; Kd = 128;
    dstBase = 851968 + (size_t)d * 512 * 128;
  } else if (b < 672) {
    int rel = b - 480; kt = rel >> 3; nt = rel & 7;
    S = Wout1; C = 512; Kd = 768; dstBase = 983040;
  } else {
    int rel = b - 672; kt = rel >> 2; nt = rel & 3;
    S = Wout2; C = 256; Kd = 512; dstBase = 1376256;
  }
  const int k0 = kt * 32, n0 = nt * 64;
  {
    int kr = tid >> 6;                // 0..3
    int n  = tid & 63;
#pragma unroll
    for (int i = 0; i < 8; i++)
      T[i * 4 + kr][n] = S[(size_t)(k0 + i * 4 + kr) * C + n0 + n];
  }
  __syncthreads();
  {
    int n = tid >> 2;                 // 0..63
    int ko = (tid & 3) * 8;           // 0,8,16,24
    ushort_t pk[8];
#pragma unroll
    for (int j = 0; j < 8; j++) pk[j] = f2bf(T[ko + j][n]);
    *(uint4*)(WT + dstBase + (size_t)(n0 + n) * Kd + k0 + ko) = *(uint4*)pk;
  }
}

// --------------------------- input projection ------------------------------
__global__ __launch_bounds__(256) void k_inproj(
    const float* __restrict__ imu, const float* __restrict__ W_in,
    const float* __restrict__ b_in, ushort_t* __restrict__ act0)
{
  int idx = blockIdx.x * 256 + threadIdx.x;   // 64000*64 exactly
  int j = idx & 63, r = idx >> 6;
  int l = r % 50;
  const float* x = imu + (size_t)r * 6;
  float acc = b_in[j];
#pragma unroll
  for (int d = 0; d < 6; d++) acc += x[d] * W_in[d * 64 + j];
  acc += (l * (1.0f / 49.0f)) * W_in[6 * 64 + j] + W_in[7 * 64 + j]; // t, rate=1
  act0[idx] = f2bf(fmaxf(acc, 0.0f));
}

// --------------------------- fused LSTM scan (round 14) ---------------------
// One block = 16 seqs of one direction, 512 thr / 8 waves, gate-quad waves.
// Steady-state step t (cur=t&1, nxt=cur^1):
//   1. issue loads X(t+2) -> xr (oldest vmem; consumed this step's end)
//   2. wide-flush h(t-1): hbuf[cur] -> Y, 1 dwordx2/thread (MODE 0)
//   3. acc = accX (has bias + x(t)@Wih); 16 Whh MFMAs on Ah from hbuf[cur]
//   4. accX = bias; 32 x@Wih MFMAs for t+1, Ax from Xs[nxt]  [independent]
//   5. pointwise(acc) -> h(t) -> hbuf[nxt]     [compiler interleaves 4 & 5]
//   6. land xr -> Xs[cur] (buffer X(t) vacated); lds_barrier
// MODE 0: wide Y flush. MODE 1: fused mean/max/final aggregation.
template <int MODE, int K>
__global__ __launch_bounds__(512, 2) void k_scan(
    const ushort_t* __restrict__ X,     // [seq*50+t][K] bf16
    const ushort_t* __restrict__ WihT,  // [2][512][K] bf16 n-major
    const ushort_t* __restrict__ WhhT,  // [2][512][128] bf16 n-major
    const float* __restrict__ bih, const float* __restrict__ bhh, // [2][512]
    ushort_t* __restrict__ Y,           // [64000][256] bf16 (MODE 0)
    ushort_t* __restrict__ aggb)        // [1280][768] bf16 (MODE 1)
{
  constexpr int NKT = K / 32;           // 2 (K=64) or 8 (K=256)
  constexpr int NKL = (K == 256) ? 1 : 0;   // Bx k-tiles in LDS
  constexpr int NKR = NKT - NKL;            // Bx k-tiles in regs
  constexpr int XST2 = K + 8;           // Xs row stride (ushorts)
  const int dir = blockIdx.y;
  const int s0 = blockIdx.x * 16;
  const int tid = threadIdx.x;
  const int wave = tid >> 6, lane = tid & 63;   // wave = hcol group 0..7
  const int cl = lane & 15, quad = lane >> 4;
  const int hcol = wave * 16 + cl;              // 0..127
  const int frow = tid >> 5, fcol = (tid & 31) * 4;  // wide-flush mapping

  __shared__ __align__(16) ushort_t hbuf[2][16][136];   //  8.5 KiB
  __shared__ __align__(16) ushort_t Xs[2][16 * XST2];   // 16.9 KiB (K=256)
  __shared__ __align__(16) ushort_t WxL[NKL ? 4 * 8 * 64 * 8 : 16]; // 32 KiB

  // register/AGPR-resident weights: 4 gates x 16 hcols for this wave
  short8 Bx[4][NKR], Bh[4][4];
  {
    const ushort_t* Wx = WihT + (size_t)dir * (512 * K);
    const ushort_t* Wd = WhhT + (size_t)dir * (512 * 128);
#pragma unroll
    for (int g = 0; g < 4; g++) {
#pragma unroll
      for (int kt = 0; kt < NKR; kt++)
        Bx[g][kt] = *(const short8*)(Wx + (size_t)(g * 128 + hcol) * K + kt * 32 + quad * 8);
#pragma unroll
      for (int kt = 0; kt < 4; kt++)
        Bh[g][kt] = *(const short8*)(Wd + (size_t)(g * 128 + hcol) * 128 + kt * 32 + quad * 8);
    }
    if (NKL) {                          // last Bx k-tile lives in LDS (per-wave)
#pragma unroll
      for (int g = 0; g < 4; g++) {
        short8 w8 = *(const short8*)(Wx + (size_t)(g * 128 + hcol) * K + NKR * 32 + quad * 8);
        *(short8*)(&WxL[((g * 8 + wave) * 64 + lane) * 8]) = w8;
      }
    }
  }
  float bias[4];
#pragma unroll
  for (int g = 0; g < 4; g++) {
    const int gc = dir * 512 + g * 128 + hcol;
    bias[g] = bih[gc] + bhh[gc];
  }

  float cst[4] = {0.f, 0.f, 0.f, 0.f};
  float sum[4] = {0.f, 0.f, 0.f, 0.f};
  float mx[4]  = {-3.0e38f, -3.0e38f, -3.0e38f, -3.0e38f};

  for (int i = tid; i < 16 * 136; i += 512) ((ushort_t*)hbuf)[i] = 0;

  {  // stage X(0)->Xs[0], X(1)->Xs[1]: wave w stages rows 2w, 2w+1
    const int t0 = dir ? 49 : 0;
    const int t1 = dir ? 48 : 1;
    if (K == 256) {
#pragma unroll
      for (int rr = 0; rr < 2; rr++) {
        *(uint2*)(&Xs[0][(wave * 2 + rr) * XST2 + lane * 4]) =
            *(const uint2*)(X + ((size_t)(s0 + wave * 2 + rr) * 50 + t0) * K + lane * 4);
        *(uint2*)(&Xs[1][(wave * 2 + rr) * XST2 + lane * 4]) =
            *(const uint2*)(X + ((size_t)(s0 + wave * 2 + rr) * 50 + t1) * K + lane * 4);
      }
    } else if (lane < 32) {
      const int rr = wave * 2 + (lane >> 4), cc = (lane & 15) * 4;
      *(uint2*)(&Xs[0][rr * XST2 + cc]) =
          *(const uint2*)(X + ((size_t)(s0 + rr) * 50 + t0) * K + cc);
      *(uint2*)(&Xs[1][rr * XST2 + cc]) =
          *(const uint2*)(X + ((size_t)(s0 + rr) * 50 + t1) * K + cc);
    }
  }
  __syncthreads();                      // hbuf zero + Xs[0..1] + WxL visible

  // pre-loop x-lookahead for t = first step: accX = bias + x(t0)@Wih
  float4v accX[4];
#pragma unroll
  for (int g = 0; g < 4; g++) accX[g] = float4v{bias[g], bias[g], bias[g], bias[g]};
#pragma unroll
  for (int kt = 0; kt < NKR; kt++) {
    short8 Ax = *(const short8*)(&Xs[0][cl * XST2 + kt * 32 + quad * 8]);
#pragma unroll
    for (int g = 0; g < 4; g++)
      accX[g] = __builtin_amdgcn_mfma_f32_16x16x32_bf16(Ax, Bx[g][kt], accX[g], 0, 0, 0);
  }
  if (NKL) {
    short8 Ax = *(const short8*)(&Xs[0][cl * XST2 + NKR * 32 + quad * 8]);
#pragma unroll
    for (int g = 0; g < 4; g++) {
      short8 Bl = *(const short8*)(&WxL[((g * 8 + wave) * 64 + lane) * 8]);
      accX[g] = __builtin_amdgcn_mfma_f32_16x16x32_bf16(Ax, Bl, accX[g], 0, 0, 0);
    }
  }
  lds_barrier();                        // pre-loop Xs[0] reads done (step 0 overwrites it)

  for (int step = 0; step < 50; step++) {
    const int t = dir ? (49 - step) : step;
    const int cur = step & 1;
    const int nxt = cur ^ 1;

    // 1. issue X(t+2) loads (oldest vmem ops of the step)
    uint2 xr0 = {0u, 0u}, xr1 = {0u, 0u};
    if (step < 48) {
      const int t2 = dir ? (t - 2) : (t + 2);
      if (K == 256) {
        xr0 = *(const uint2*)(X + ((size_t)(s0 + wave * 2 + 0) * 50 + t2) * K + lane * 4);
        xr1 = *(const uint2*)(X + ((size_t)(s0 + wave * 2 + 1) * 50 + t2) * K + lane * 4);
      } else if (lane < 32) {
        xr0 = *(const uint2*)(X + ((size_t)(s0 + wave * 2 + (lane >> 4)) * 50 + t2) * K + (lane & 15) * 4);
      }
    }

    // 2. wide flush of h(t-1) from hbuf[cur] (stores younger than loads)
    if (MODE == 0 && step > 0) {
      const int tp = dir ? (t + 1) : (t - 1);
      uint2 hv = *(const uint2*)(&hbuf[cur][frow][fcol]);
      *(uint2*)(Y + ((size_t)(s0 + frow) * 50 + tp) * 256 + dir * 128 + fcol) = hv;
    }

    // 3. recurrence path: acc = accX; 16 Whh MFMAs on h(t-1)
    float4v acc[4];
#pragma unroll
    for (int g = 0; g < 4; g++) acc[g] = accX[g];
#pragma unroll
    for (int kt = 0; kt < 4; kt++) {
      short8 Ah = *(const short8*)(&hbuf[cur][cl][kt * 32 + quad * 8]);
#pragma unroll
      for (int g = 0; g < 4; g++)
        acc[g] = __builtin_amdgcn_mfma_f32_16x16x32_bf16(Ah, Bh[g][kt], acc[g], 0, 0, 0);
    }

    // 4. x-lookahead for t+1 (independent of 3/5 -> fills MFMA pipe)
    if (step < 49) {
#pragma unroll
      for (int g = 0; g < 4; g++) accX[g] = float4v{bias[g], bias[g], bias[g], bias[g]};
#pragma unroll
      for (int kt = 0; kt < NKR; kt++) {
        short8 Ax = *(const short8*)(&Xs[nxt][cl * XST2 + kt * 32 + quad * 8]);
#pragma unroll
        for (int g = 0; g < 4; g++)
          accX[g] = __builtin_amdgcn_mfma_f32_16x16x32_bf16(Ax, Bx[g][kt], accX[g], 0, 0, 0);
      }
      if (NKL) {
        short8 Ax = *(const short8*)(&Xs[nxt][cl * XST2 + NKR * 32 + quad * 8]);
#pragma unroll
        for (int g = 0; g < 4; g++) {
          short8 Bl = *(const short8*)(&WxL[((g * 8 + wave) * 64 + lane) * 8]);
          accX[g] = __builtin_amdgcn_mfma_f32_16x16x32_bf16(Ax, Bl, accX[g], 0, 0, 0);
        }
      }
    }

    // 5. pointwise (VALU/trans; interleaves with 4's MFMAs)
#pragma unroll
    for (int r = 0; r < 4; r++) {
      float ii = sigmoidf_(acc[0][r]);
      float ff = sigmoidf_(acc[1][r]);
      float gc = tanhf_(acc[2][r]);
      float oo = sigmoidf_(acc[3][r]);
      float c2 = ff * cst[r] + ii * gc;
      cst[r] = c2;
      float h = oo * tanhf_(c2);
      hbuf[nxt][quad * 4 + r][hcol] = f2bf(h);
      if (MODE == 1) {
        sum[r] += h;
        mx[r] = fmaxf(mx[r], h);
        if (step == 49) {               // h here is h_n of this dir
          const size_t seq = s0 + quad * 4 + r;
          const int cc = dir * 128 + hcol;
          aggb[seq * 768 + cc]       = f2bf(sum[r] * (1.0f / 50.0f));
          aggb[seq * 768 + 256 + cc] = f2bf(mx[r]);
          aggb[seq * 768 + 512 + cc] = f2bf(h);
        }
      }
    }

    // 6. land X(t+2) into Xs[cur] (X(t)'s buffer; its last read was step-1)
    if (step < 48) {
      if (K == 256) {
        *(uint2*)(&Xs[cur][(wave * 2 + 0) * XST2 + lane * 4]) = xr0;
        *(uint2*)(&Xs[cur][(wave * 2 + 1) * XST2 + lane * 4]) = xr1;
      } else if (lane < 32) {
        *(uint2*)(&Xs[cur][(wave * 2 + (lane >> 4)) * XST2 + (lane & 15) * 4]) = xr0;
      }
    }
    lds_barrier();                      // h + Xs visible; vmcnt NOT drained
  }

  if (MODE == 0) {                      // flush h(49) (in hbuf[0]: 49&1^1)
    const int tl = dir ? 0 : 49;
    uint2 hv = *(const uint2*)(&hbuf[0][frow][fcol]);
    *(uint2*)(Y + ((size_t)(s0 + frow) * 50 + tl) * 256 + dir * 128 + fcol) = hv;
  }
}

// --------------------------- fused head -------------------------------------
__global__ __launch_bounds__(512, 1) void k_head(
    const ushort_t* __restrict__ aggb,  // [1280][768] bf16
    const ushort_t* __restrict__ W1T,   // [512][768] bf16
    const float* __restrict__ b1, const float* __restrict__ ln_g,
    const float* __restrict__ ln_b,
    const ushort_t* __restrict__ W2T,   // [256][512] bf16
    const float* __restrict__ b2, float* __restrict__ out) // [1280][256]
{
  __shared__ __align__(16) char smem[78336];
  ushort_t* AsB = (ushort_t*)smem;            // [2][64*32]   (8 KiB)
  ushort_t* BsB = (ushort_t*)(smem + 8192);   // [2][512*32]  (64 KiB)
  ushort_t* hn  = (ushort_t*)smem;            // [64][520] aliased (66.6 KiB)
  float* partS  = (float*)(smem + 73728);     // [64][8]
  float* partQ  = partS + 512;                // [64][8]
  float* muS    = partQ + 512;                // [64]
  float* rsS    = muS + 64;                   // [64]

  const int m0 = blockIdx.x * 64;
  const int tid = threadIdx.x;
  const int wave = tid >> 6, lane = tid & 63;
  const int cl = lane & 15, quad = lane >> 4;
  const int srow = lane >> 2, scol = (lane & 3) * 8;

  float4v acc1[4][4];
#pragma unroll
  for (int i = 0; i < 4; i++)
#pragma unroll
    for (int v = 0; v < 4; v++) acc1[i][v] = float4v{0.f, 0.f, 0.f, 0.f};

#define STAGE1(buf, kb)                                                       \
  {                                                                           \
    if (wave < 4)                                                             \
      gload16(aggb + (size_t)(m0 + wave * 16 + srow) * 768 + (kb) + scol,     \
              AsB + (buf) * 2048 + wave * 16 * 32 + lane * 8);                \
    _Pragma("unroll")                                                         \
    for (int j = 0; j < 4; j++)                                               \
      gload16(W1T + (size_t)(wave * 64 + j * 16 + srow) * 768 + (kb) + scol,  \
              BsB + (buf) * 16384 + (wave * 64 + j * 16) * 32 + lane * 8);    \
  }

  STAGE1(0, 0)
  for (int kb = 0; kb < 768; kb += 32) {
    const int cur = (kb >> 5) & 1;
    __syncthreads();
    if (kb + 32 < 768) STAGE1(cur ^ 1, kb + 32)
    short8 Af[4], Bf[4];
#pragma unroll
    for (int i = 0; i < 4; i++)
      Af[i] = *(const short8*)(AsB + cur * 2048 + (i * 16 + cl) * 32 + quad * 8);
#pragma unroll
    for (int v = 0; v < 4; v++)
      Bf[v] = *(const short8*)(BsB + cur * 16384 + (wave * 64 + v * 16 + cl) * 32 + quad * 8);
#pragma unroll
    for (int i = 0; i < 4; i++)
#pragma unroll
      for (int v = 0; v < 4; v++)
        acc1[i][v] = __builtin_amdgcn_mfma_f32_16x16x32_bf16(Af[i], Bf[v], acc1[i][v], 0, 0, 0);
  }
#undef STAGE1
  __syncthreads();          // all waves done with AsB/BsB (hn aliases them)

  float bcol[4], lg[4], lb[4];
#pragma unroll
  for (int v = 0; v < 4; v++) {
    int col = wave * 64 + v * 16 + cl;
    bcol[v] = b1[col]; lg[v] = ln_g[col]; lb[v] = ln_b[col];
  }

#pragma unroll
  for (int i = 0; i < 4; i++) {
#pragma unroll
    for (int r = 0; r < 4; r++) {
      float s = 0.f, q = 0.f;
#pragma unroll
      for (int v = 0; v < 4; v++) {
        float x = acc1[i][v][r] + bcol[v];
        s += x; q += x * x;
      }
#pragma unroll
      for (int m = 1; m <= 8; m <<= 1) {
        s += __shfl_xor(s, m);
        q += __shfl_xor(q, m);
      }
      if (cl == 0) {
        int row = i * 16 + quad * 4 + r;
        partS[row * 8 + wave] = s;
        partQ[row * 8 + wave] = q;
      }
    }
  }
  __syncthreads();
  if (tid < 64) {
    float s = 0.f, q = 0.f;
#pragma unroll
    for (int w = 0; w < 8; w++) { s += partS[tid * 8 + w]; q += partQ[tid * 8 + w]; }
    float mu = s * (1.0f / 512.0f);
    float var = q * (1.0f / 512.0f) - mu * mu;
    muS[tid] = mu;
    rsS[tid] = rsqrtf(var + 1e-5f);
  }
  __syncthreads();

#pragma unroll
  for (int i = 0; i < 4; i++) {
#pragma unroll
    for (int r = 0; r < 4; r++) {
      int row = i * 16 + quad * 4 + r;
      float mu = muS[row], rs = rsS[row];
#pragma unroll
      for (int v = 0; v < 4; v++) {
        int col = wave * 64 + v * 16 + cl;
        float x = acc1[i][v][r] + bcol[v];
        float y = (x - mu) * rs * lg[v] + lb[v];
        hn[row * 520 + col] = f2bf(fmaxf(y, 0.0f));
      }
    }
  }
  __syncthreads();

  float4v acc2[4][2];
#pragma unroll
  for (int i = 0; i < 4; i++)
#pragma unroll
    for (int u = 0; u < 2; u++) acc2[i][u] = float4v{0.f, 0.f, 0.f, 0.f};
  for (int kt = 0; kt < 16; kt++) {
    short8 Af2[4], Bf2[2];
#pragma unroll
    for (int u = 0; u < 2; u++)
      Bf2[u] = *(const short8*)(W2T + (size_t)(wave * 32 + u * 16 + cl) * 512 + kt * 32 + quad * 8);
#pragma unroll
    for (int i = 0; i < 4; i++)
      Af2[i] = *(const short8*)(hn + (i * 16 + cl) * 520 + kt * 32 + quad * 8);
#pragma unroll
    for (int i = 0; i < 4; i++)
#pragma unroll
      for (int u = 0; u < 2; u++)
        acc2[i][u] = __builtin_amdgcn_mfma_f32_16x16x32_bf16(Af2[i], Bf2[u], acc2[i][u], 0, 0, 0);
  }
#pragma unroll
  for (int u = 0; u < 2; u++) {
    int col = wave * 32 + u * 16 + cl;
    float bb = b2[col];
#pragma unroll
    for (int i = 0; i < 4; i++)
#pragma unroll
      for (int r = 0; r < 4; r++)
        out[(size_t)(m0 + i * 16 + quad * 4 + r) * 256 + col] = acc2[i][u][r] + bb;
  }
}

// --------------------------- launcher --------------------------------------
extern "C" void kernel_launch(void* const* d_in, const int* in_sizes, int n_in,
                              void* d_out, int out_size, void* d_ws, size_t ws_size,
                              hipStream_t stream)
{
  (void)in_sizes; (void)n_in; (void)out_size; (void)ws_size;
  const float* imu   = (const float*)d_in[0];
  const float* W_in  = (const float*)d_in[1];
  const float* b_in  = (const float*)d_in[2];
  const float* Wih0  = (const float*)d_in[3];
  const float* Whh0  = (const float*)d_in[4];
  const float* bih0  = (const float*)d_in[5];
  const float* bhh0  = (const float*)d_in[6];
  const float* Wih1  = (const float*)d_in[7];
  const float* Whh1  = (const float*)d_in[8];
  const float* bih1  = (const float*)d_in[9];
  const float* bhh1  = (const float*)d_in[10];
  const float* Wih2  = (const float*)d_in[11];
  const float* Whh2  = (const float*)d_in[12];
  const float* bih2  = (const float*)d_in[13];
  const float* bhh2  = (const float*)d_in[14];
  const float* Wout1 = (const float*)d_in[15];
  const float* bout1 = (const float*)d_in[16];
  const float* ln_g  = (const float*)d_in[17];
  const float* ln_b  = (const float*)d_in[18];
  const float* Wout2 = (const float*)d_in[19];
  const float* bout2 = (const float*)d_in[20];
  float* out = (float*)d_out;
  char* ws = (char*)d_ws;

  // ws layout (bytes)
  const size_t ACT0_OFF = 0;                      // 8,192,000  (64000*64*2)
  const size_t YA_OFF   = 8192000;                // 32,768,000 (64000*256*2)
  const size_t YB_OFF   = 40960000;               // 32,768,000
  const size_t WT_OFF   = 73728000;               // 3,014,656  (1,507,328 bf16)

  ushort_t* act0 = (ushort_t*)(ws + ACT0_OFF);
  ushort_t* Ya   = (ushort_t*)(ws + YA_OFF);
  ushort_t* Yb   = (ushort_t*)(ws + YB_OFF);
  ushort_t* WT   = (ushort_t*)(ws + WT_OFF);
  ushort_t* aggb = (ushort_t*)(ws + 0);           // reuses act0 region (dead by then)

  ushort_t* WT_ih0 = WT + 0;
  ushort_t* WT_ih1 = WT + 65536;
  ushort_t* WT_ih2 = WT + 327680;
  ushort_t* WT_hh0 = WT + 589824;
  ushort_t* WT_hh1 = WT + 720896;
  ushort_t* WT_hh2 = WT + 851968;
  ushort_t* W1T    = WT + 983040;
  ushort_t* W2T    = WT + 1376256;

  k_prep<<<736, 256, 0, stream>>>(Wih0, Wih1, Wih2, Whh0, Whh1, Whh2,
                                  Wout1, Wout2, WT);
  k_inproj<<<16000, 256, 0, stream>>>(imu, W_in, b_in, act0);

  const dim3 sg(80, 2);
  k_scan<0, 64><<<sg, 512, 0, stream>>>(act0, WT_ih0, WT_hh0, bih0, bhh0, Ya, aggb);
  k_scan<0, 256><<<sg, 512, 0, stream>>>(Ya, WT_ih1, WT_hh1, bih1, bhh1, Yb, aggb);
  k_scan<1, 256><<<sg, 512, 0, stream>>>(Yb, WT_ih2, WT_hh2, bih2, bhh2, Ya, aggb);

  k_head<<<20, 512, 0, stream>>>(aggb, W1T, bout1, ln_g, ln_b, W2T, bout2, out);
}

// Round 10
// 360.270 us; speedup vs baseline: 1.0989x; 1.0989x over previous
//
#include <hip/hip_runtime.h>
#include <stdint.h>

// ---------------------------------------------------------------------------
// TimeAwareIMULSTMEncoder on MI355X (gfx950) — round 15 (consolidation)
// Plateau evidence (rounds 7-14): per-step scan time invariant to MFMA count,
// wave layout, barrier count, vmcnt policy, and in-wave lookahead -> step is
// ~50% issue-occupied (MFMA+VALU+trans+LDS) with lockstep-unfillable latency
// gaps; register file (192 weight regs) pins occupancy at 2 waves/SIMD.
// This round keeps the best verified scan (round 13) and adds only
// verified-good pieces:
//  * wide Y flush from hbuf (round 14, verified): 1 dwordx2/thread instead
//    of 4 scattered 2-B stores -> WRITE 38.4->8.3 MB (Y stays in L2 for the
//    next layer's X reads), FETCH 31->23 MB, k_scan -1.3 us.
//  * k_prep + k_inproj fused into ONE dispatch (independent work, disjoint
//    ws writes) -> they run concurrently instead of serialized.
// ---------------------------------------------------------------------------

typedef unsigned short ushort_t;
typedef short short8 __attribute__((ext_vector_type(8)));     // 8 bf16 (4 VGPRs)
typedef float float4v __attribute__((ext_vector_type(4)));    // MFMA acc

#define DEV_INLINE __device__ __forceinline__

DEV_INLINE ushort_t f2bf(float f) {                 // RNE f32 -> bf16 bits
  union { float f; unsigned u; } v; v.f = f;
  unsigned r = v.u + 0x7fffu + ((v.u >> 16) & 1u);
  return (ushort_t)(r >> 16);
}
DEV_INLINE float sigmoidf_(float x) {
  return __builtin_amdgcn_rcpf(1.0f + __expf(-x));
}
DEV_INLINE float tanhf_(float x) {                  // 1 - 2/(1+e^{2x}); safe at +-inf
  return 1.0f - 2.0f * __builtin_amdgcn_rcpf(1.0f + __expf(2.0f * x));
}

// LDS-only barrier: ds-op completion + rendezvous, no vmcnt drain.
DEV_INLINE void lds_barrier() {
  asm volatile("s_waitcnt lgkmcnt(0)\n\ts_barrier" ::: "memory");
}

// async global->LDS, 16B per lane; dst must be wave-uniform base + lane*16.
DEV_INLINE void gload16(const ushort_t* g, ushort_t* l) {
  __builtin_amdgcn_global_load_lds(
      (const __attribute__((address_space(1))) unsigned int*)g,
      (__attribute__((address_space(3))) unsigned int*)l, 16, 0, 0);
}

// ----------------- fused weight prep + input projection ---------------------
// blocks 0..735: tiled transpose of all weights to bf16 n-major (k_prep).
// blocks 736..16735: input projection imu -> act0 (k_inproj).
// Independent work, disjoint destinations -> one concurrent dispatch.
__global__ __launch_bounds__(256) void k_pre(
    const float* __restrict__ Wih0, const float* __restrict__ Wih1,
    const float* __restrict__ Wih2, const float* __restrict__ Whh0,
    const float* __restrict__ Whh1, const float* __restrict__ Whh2,
    const float* __restrict__ Wout1, const float* __restrict__ Wout2,
    ushort_t* __restrict__ WT,
    const float* __restrict__ imu, const float* __restrict__ W_in,
    const float* __restrict__ b_in, ushort_t* __restrict__ act0)
{
  __shared__ float T[32][65];
  const int tid = threadIdx.x;

  if (blockIdx.x >= 736) {              // ---- input projection ----
    int idx = (blockIdx.x - 736) * 256 + tid;   // 64000*64 exactly
    int j = idx & 63, r = idx >> 6;
    int l = r % 50;
    const float* x = imu + (size_t)r * 6;
    float acc = b_in[j];
#pragma unroll
    for (int d = 0; d < 6; d++) acc += x[d] * W_in[d * 64 + j];
    acc += (l * (1.0f / 49.0f)) * W_in[6 * 64 + j] + W_in[7 * 64 + j]; // t, rate=1
    act0[idx] = f2bf(fmaxf(acc, 0.0f));
    return;
  }

  // ---- weight prep (tiled transpose) ----
  const int b = blockIdx.x;
  const float* S; int Kd, C; size_t dstBase; int kt, nt;
  if (b < 32) {
    int rel = b; int d = (rel >> 3) / 2; kt = (rel >> 3) & 1; nt = rel & 7;
    S = Wih0 + (size_t)d * 64 * 512; C = 512; Kd = 64;
    dstBase = 0 + (size_t)d * 512 * 64;
  } else if (b < 160) {
    int rel = b - 32; int d = (rel >> 3) / 8; kt = (rel >> 3) & 7; nt = rel & 7;
    S = Wih1 + (size_t)d * 256 * 512; C = 512; Kd = 256;
    dstBase = 65536 + (size_t)d * 512 * 256;
  } else if (b < 288) {
    int rel = b - 160; int d = (rel >> 3) / 8; kt = (rel >> 3) & 7; nt = rel & 7;
    S = Wih2 + (size_t)d * 256 * 512; C = 512; Kd = 256;
    dstBase = 327680 + (size_t)d * 512 * 256;
  } else if (b < 352) {
    int rel = b - 288; int d = (rel >> 3) / 4; kt = (rel >> 3) & 3; nt = rel & 7;
    S = Whh0 + (size_t)d * 128 * 512; C = 512; Kd = 128;
    dstBase = 589824 + (size_t)d * 512 * 128;
  } else if (b < 416) {
    int rel = b - 352; int d = (rel >> 3) / 4; kt = (rel >> 3) & 3; nt = rel & 7;
    S = Whh1 + (size_t)d * 128 * 512; C = 512; Kd = 128;
    dstBase = 720896 + (size_t)d * 512 * 128;
  } else if (b < 480) {
    int rel = b - 416; int d = (rel >> 3) / 4; kt = (rel >> 3) & 3; nt = rel & 7;
    S = Whh2 + (size_t)d * 128 * 512; C = 512; Kd = 128;
    dstBase = 851968 + (size_t)d * 512 * 128;
  } else if (b < 672) {
    int rel = b - 480; kt = rel >> 3; nt = rel & 7;
    S = Wout1; C = 512; Kd = 768; dstBase = 983040;
  } else {
    int rel = b - 672; kt = rel >> 2; nt = rel & 3;
    S = Wout2; C = 256; Kd = 512; dstBase = 1376256;
  }
  const int k0 = kt * 32, n0 = nt * 64;
  {
    int kr = tid >> 6;                // 0..3
    int n  = tid & 63;
#pragma unroll
    for (int i = 0; i < 8; i++)
      T[i * 4 + kr][n] = S[(size_t)(k0 + i * 4 + kr) * C + n0 + n];
  }
  __syncthreads();
  {
    int n = tid >> 2;                 // 0..63
    int ko = (tid & 3) * 8;           // 0,8,16,24
    ushort_t pk[8];
#pragma unroll
    for (int j = 0; j < 8; j++) pk[j] = f2bf(T[ko + j][n]);
    *(uint4*)(WT + dstBase + (size_t)(n0 + n) * Kd + k0 + ko) = *(uint4*)pk;
  }
}

// --------------------------- fused LSTM scan (round 15) ---------------------
// One block = 16 seqs of one direction, 512 thr / 8 waves, gate-quad waves.
// Wave w: gates 0..3 for hcols w*16+cl. Per step:
//   wide-flush h(t-1) from hbuf[cur] (1 dwordx2/thread, MODE 0);
//   read Ax (K/32 b128 from Xs) + Ah (4 b128 from hbuf); prefetch next X
//   rows to VGPRs; 4 gate accs = bias + x@Wih + h@Whh (all-reg weights);
//   in-register LSTM pointwise (lane holds i,f,g,o of 4 cells); write h to
//   hbuf; land X prefetch; ONE LDS-only barrier (no vmcnt drain).
// MODE 0: wide Y flush. MODE 1: fused mean/max/final aggregation.
template <int MODE, int K>
__global__ __launch_bounds__(512, 2) void k_scan(
    const ushort_t* __restrict__ X,     // [seq*50+t][K] bf16
    const ushort_t* __restrict__ WihT,  // [2][512][K] bf16 n-major
    const ushort_t* __restrict__ WhhT,  // [2][512][128] bf16 n-major
    const float* __restrict__ bih, const float* __restrict__ bhh, // [2][512]
    ushort_t* __restrict__ Y,           // [64000][256] bf16 (MODE 0)
    ushort_t* __restrict__ aggb)        // [1280][768] bf16 (MODE 1)
{
  constexpr int NKT = K / 32;           // 2 (K=64) or 8 (K=256)
  constexpr int XST2 = K + 8;           // Xs row stride (ushorts)
  const int dir = blockIdx.y;
  const int s0 = blockIdx.x * 16;
  const int tid = threadIdx.x;
  const int wave = tid >> 6, lane = tid & 63;   // wave = hcol group 0..7
  const int cl = lane & 15, quad = lane >> 4;
  const int hcol = wave * 16 + cl;              // 0..127
  const int frow = tid >> 5, fcol = (tid & 31) * 4;  // wide-flush mapping

  __shared__ __align__(16) ushort_t hbuf[2][16][136];   //  8.5 KiB
  __shared__ __align__(16) ushort_t Xs[2][16 * XST2];   // 16.5 KiB (K=256)

  // register/AGPR-resident weights: 4 gates x 16 hcols for this wave
  short8 Bx[4][NKT], Bh[4][4];
  {
    const ushort_t* Wx = WihT + (size_t)dir * (512 * K);
    const ushort_t* Wd = WhhT + (size_t)dir * (512 * 128);
#pragma unroll
    for (int g = 0; g < 4; g++) {
#pragma unroll
      for (int kt = 0; kt < NKT; kt++)
        Bx[g][kt] = *(const short8*)(Wx + (size_t)(g * 128 + hcol) * K + kt * 32 + quad * 8);
#pragma unroll
      for (int kt = 0; kt < 4; kt++)
        Bh[g][kt] = *(const short8*)(Wd + (size_t)(g * 128 + hcol) * 128 + kt * 32 + quad * 8);
    }
  }
  float bias[4];
#pragma unroll
  for (int g = 0; g < 4; g++) {
    const int gc = dir * 512 + g * 128 + hcol;
    bias[g] = bih[gc] + bhh[gc];
  }

  float cst[4] = {0.f, 0.f, 0.f, 0.f};
  float sum[4] = {0.f, 0.f, 0.f, 0.f};
  float mx[4]  = {-3.0e38f, -3.0e38f, -3.0e38f, -3.0e38f};

  for (int i = tid; i < 16 * 136; i += 512) ((ushort_t*)hbuf)[i] = 0;

  {  // stage X(step 0): 16 rows; wave w stages rows 2w, 2w+1 (8B/lane)
    const int tt = dir ? 49 : 0;
    if (K == 256) {
      uint2 v0 = *(const uint2*)(X + ((size_t)(s0 + wave * 2 + 0) * 50 + tt) * K + lane * 4);
      uint2 v1 = *(const uint2*)(X + ((size_t)(s0 + wave * 2 + 1) * 50 + tt) * K + lane * 4);
      *(uint2*)(&Xs[0][(wave * 2 + 0) * XST2 + lane * 4]) = v0;
      *(uint2*)(&Xs[0][(wave * 2 + 1) * XST2 + lane * 4]) = v1;
    } else if (lane < 32) {
      uint2 v0 = *(const uint2*)(X + ((size_t)(s0 + wave * 2 + (lane >> 4)) * 50 + tt) * K + (lane & 15) * 4);
      *(uint2*)(&Xs[0][(wave * 2 + (lane >> 4)) * XST2 + (lane & 15) * 4]) = v0;
    }
  }
  __syncthreads();                      // hbuf zero + Xs[0] visible (full sync ok once)

  for (int step = 0; step < 50; step++) {
    const int t = dir ? (49 - step) : step;
    const int cur = step & 1;

    // wide flush of h(t-1) from hbuf[cur] (Y stays L2-resident for next layer)
    if (MODE == 0 && step > 0) {
      const int tp = dir ? (t + 1) : (t - 1);
      uint2 hv = *(const uint2*)(&hbuf[cur][frow][fcol]);
      *(uint2*)(Y + ((size_t)(s0 + frow) * 50 + tp) * 256 + dir * 128 + fcol) = hv;
    }

    // A fragments (shared across the wave's 4 gates)
    short8 Ax[NKT], Ah[4];
#pragma unroll
    for (int kt = 0; kt < NKT; kt++)
      Ax[kt] = *(const short8*)(&Xs[cur][cl * XST2 + kt * 32 + quad * 8]);
#pragma unroll
    for (int kt = 0; kt < 4; kt++)
      Ah[kt] = *(const short8*)(&hbuf[cur][cl][kt * 32 + quad * 8]);

    // prefetch next step's X rows into VGPRs (landed after pointwise)
    uint2 xr0 = {0u, 0u}, xr1 = {0u, 0u};
    if (step < 49) {
      const int t1 = dir ? (t - 1) : (t + 1);
      if (K == 256) {
        xr0 = *(const uint2*)(X + ((size_t)(s0 + wave * 2 + 0) * 50 + t1) * K + lane * 4);
        xr1 = *(const uint2*)(X + ((size_t)(s0 + wave * 2 + 1) * 50 + t1) * K + lane * 4);
      } else if (lane < 32) {
        xr0 = *(const uint2*)(X + ((size_t)(s0 + wave * 2 + (lane >> 4)) * 50 + t1) * K + (lane & 15) * 4);
      }
    }

    // 4 gate accumulators: bias + x@Wih + h@Whh
    float4v acc[4];
#pragma unroll
    for (int g = 0; g < 4; g++) acc[g] = float4v{bias[g], bias[g], bias[g], bias[g]};
#pragma unroll
    for (int kt = 0; kt < NKT; kt++)
#pragma unroll
      for (int g = 0; g < 4; g++)
        acc[g] = __builtin_amdgcn_mfma_f32_16x16x32_bf16(Ax[kt], Bx[g][kt], acc[g], 0, 0, 0);
#pragma unroll
    for (int kt = 0; kt < 4; kt++)
#pragma unroll
      for (int g = 0; g < 4; g++)
        acc[g] = __builtin_amdgcn_mfma_f32_16x16x32_bf16(Ah[kt], Bh[g][kt], acc[g], 0, 0, 0);

    // in-register pointwise: lane holds i,f,g,o of cells (quad*4+r, hcol)
#pragma unroll
    for (int r = 0; r < 4; r++) {
      float ii = sigmoidf_(acc[0][r]);
      float ff = sigmoidf_(acc[1][r]);
      float gc = tanhf_(acc[2][r]);
      float oo = sigmoidf_(acc[3][r]);
      float c2 = ff * cst[r] + ii * gc;
      cst[r] = c2;
      float h = oo * tanhf_(c2);
      hbuf[cur ^ 1][quad * 4 + r][hcol] = f2bf(h);
      if (MODE == 1) {
        sum[r] += h;
        mx[r] = fmaxf(mx[r], h);
        if (step == 49) {               // h here is h_n of this dir
          const size_t seq = s0 + quad * 4 + r;
          const int cc = dir * 128 + hcol;
          aggb[seq * 768 + cc]       = f2bf(sum[r] * (1.0f / 50.0f));
          aggb[seq * 768 + 256 + cc] = f2bf(mx[r]);
          aggb[seq * 768 + 512 + cc] = f2bf(h);
        }
      }
    }

    // land X prefetch into the other buffer (dep-based vmcnt wait only here)
    if (step < 49) {
      if (K == 256) {
        *(uint2*)(&Xs[cur ^ 1][(wave * 2 + 0) * XST2 + lane * 4]) = xr0;
        *(uint2*)(&Xs[cur ^ 1][(wave * 2 + 1) * XST2 + lane * 4]) = xr1;
      } else if (lane < 32) {
        *(uint2*)(&Xs[cur ^ 1][(wave * 2 + (lane >> 4)) * XST2 + (lane & 15) * 4]) = xr0;
      }
    }
    lds_barrier();                      // h + Xs visible; vmcnt NOT drained
  }

  if (MODE == 0) {                      // flush h(49) (step 49 wrote hbuf[0])
    const int tl = dir ? 0 : 49;
    uint2 hv = *(const uint2*)(&hbuf[0][frow][fcol]);
    *(uint2*)(Y + ((size_t)(s0 + frow) * 50 + tl) * 256 + dir * 128 + fcol) = hv;
  }
}

// --------------------------- fused head -------------------------------------
__global__ __launch_bounds__(512, 1) void k_head(
    const ushort_t* __restrict__ aggb,  // [1280][768] bf16
    const ushort_t* __restrict__ W1T,   // [512][768] bf16
    const float* __restrict__ b1, const float* __restrict__ ln_g,
    const float* __restrict__ ln_b,
    const ushort_t* __restrict__ W2T,   // [256][512] bf16
    const float* __restrict__ b2, float* __restrict__ out) // [1280][256]
{
  __shared__ __align__(16) char smem[78336];
  ushort_t* AsB = (ushort_t*)smem;            // [2][64*32]   (8 KiB)
  ushort_t* BsB = (ushort_t*)(smem + 8192);   // [2][512*32]  (64 KiB)
  ushort_t* hn  = (ushort_t*)smem;            // [64][520] aliased (66.6 KiB)
  float* partS  = (float*)(smem + 73728);     // [64][8]
  float* partQ  = partS + 512;                // [64][8]
  float* muS    = partQ + 512;                // [64]
  float* rsS    = muS + 64;                   // [64]

  const int m0 = blockIdx.x * 64;
  const int tid = threadIdx.x;
  const int wave = tid >> 6, lane = tid & 63;
  const int cl = lane & 15, quad = lane >> 4;
  const int srow = lane >> 2, scol = (lane & 3) * 8;

  float4v acc1[4][4];
#pragma unroll
  for (int i = 0; i < 4; i++)
#pragma unroll
    for (int v = 0; v < 4; v++) acc1[i][v] = float4v{0.f, 0.f, 0.f, 0.f};

#define STAGE1(buf, kb)                                                       \
  {                                                                           \
    if (wave < 4)                                                             \
      gload16(aggb + (size_t)(m0 + wave * 16 + srow) * 768 + (kb) + scol,     \
              AsB + (buf) * 2048 + wave * 16 * 32 + lane * 8);                \
    _Pragma("unroll")                                                         \
    for (int j = 0; j < 4; j++)                                               \
      gload16(W1T + (size_t)(wave * 64 + j * 16 + srow) * 768 + (kb) + scol,  \
              BsB + (buf) * 16384 + (wave * 64 + j * 16) * 32 + lane * 8);    \
  }

  STAGE1(0, 0)
  for (int kb = 0; kb < 768; kb += 32) {
    const int cur = (kb >> 5) & 1;
    __syncthreads();
    if (kb + 32 < 768) STAGE1(cur ^ 1, kb + 32)
    short8 Af[4], Bf[4];
#pragma unroll
    for (int i = 0; i < 4; i++)
      Af[i] = *(const short8*)(AsB + cur * 2048 + (i * 16 + cl) * 32 + quad * 8);
#pragma unroll
    for (int v = 0; v < 4; v++)
      Bf[v] = *(const short8*)(BsB + cur * 16384 + (wave * 64 + v * 16 + cl) * 32 + quad * 8);
#pragma unroll
    for (int i = 0; i < 4; i++)
#pragma unroll
      for (int v = 0; v < 4; v++)
        acc1[i][v] = __builtin_amdgcn_mfma_f32_16x16x32_bf16(Af[i], Bf[v], acc1[i][v], 0, 0, 0);
  }
#undef STAGE1
  __syncthreads();          // all waves done with AsB/BsB (hn aliases them)

  float bcol[4], lg[4], lb[4];
#pragma unroll
  for (int v = 0; v < 4; v++) {
    int col = wave * 64 + v * 16 + cl;
    bcol[v] = b1[col]; lg[v] = ln_g[col]; lb[v] = ln_b[col];
  }

#pragma unroll
  for (int i = 0; i < 4; i++) {
#pragma unroll
    for (int r = 0; r < 4; r++) {
      float s = 0.f, q = 0.f;
#pragma unroll
      for (int v = 0; v < 4; v++) {
        float x = acc1[i][v][r] + bcol[v];
        s += x; q += x * x;
      }
#pragma unroll
      for (int m = 1; m <= 8; m <<= 1) {
        s += __shfl_xor(s, m);
        q += __shfl_xor(q, m);
      }
      if (cl == 0) {
        int row = i * 16 + quad * 4 + r;
        partS[row * 8 + wave] = s;
        partQ[row * 8 + wave] = q;
      }
    }
  }
  __syncthreads();
  if (tid < 64) {
    float s = 0.f, q = 0.f;
#pragma unroll
    for (int w = 0; w < 8; w++) { s += partS[tid * 8 + w]; q += partQ[tid * 8 + w]; }
    float mu = s * (1.0f / 512.0f);
    float var = q * (1.0f / 512.0f) - mu * mu;
    muS[tid] = mu;
    rsS[tid] = rsqrtf(var + 1e-5f);
  }
  __syncthreads();

#pragma unroll
  for (int i = 0; i < 4; i++) {
#pragma unroll
    for (int r = 0; r < 4; r++) {
      int row = i * 16 + quad * 4 + r;
      float mu = muS[row], rs = rsS[row];
#pragma unroll
      for (int v = 0; v < 4; v++) {
        int col = wave * 64 + v * 16 + cl;
        float x = acc1[i][v][r] + bcol[v];
        float y = (x - mu) * rs * lg[v] + lb[v];
        hn[row * 520 + col] = f2bf(fmaxf(y, 0.0f));
      }
    }
  }
  __syncthreads();

  float4v acc2[4][2];
#pragma unroll
  for (int i = 0; i < 4; i++)
#pragma unroll
    for (int u = 0; u < 2; u++) acc2[i][u] = float4v{0.f, 0.f, 0.f, 0.f};
  for (int kt = 0; kt < 16; kt++) {
    short8 Af2[4], Bf2[2];
#pragma unroll
    for (int u = 0; u < 2; u++)
      Bf2[u] = *(const short8*)(W2T + (size_t)(wave * 32 + u * 16 + cl) * 512 + kt * 32 + quad * 8);
#pragma unroll
    for (int i = 0; i < 4; i++)
      Af2[i] = *(const short8*)(hn + (i * 16 + cl) * 520 + kt * 32 + quad * 8);
#pragma unroll
    for (int i = 0; i < 4; i++)
#pragma unroll
      for (int u = 0; u < 2; u++)
        acc2[i][u] = __builtin_amdgcn_mfma_f32_16x16x32_bf16(Af2[i], Bf2[u], acc2[i][u], 0, 0, 0);
  }
#pragma unroll
  for (int u = 0; u < 2; u++) {
    int col = wave * 32 + u * 16 + cl;
    float bb = b2[col];
#pragma unroll
    for (int i = 0; i < 4; i++)
#pragma unroll
      for (int r = 0; r < 4; r++)
        out[(size_t)(m0 + i * 16 + quad * 4 + r) * 256 + col] = acc2[i][u][r] + bb;
  }
}

// --------------------------- launcher --------------------------------------
extern "C" void kernel_launch(void* const* d_in, const int* in_sizes, int n_in,
                              void* d_out, int out_size, void* d_ws, size_t ws_size,
                              hipStream_t stream)
{
  (void)in_sizes; (void)n_in; (void)out_size; (void)ws_size;
  const float* imu   = (const float*)d_in[0];
  const float* W_in  = (const float*)d_in[1];
  const float* b_in  = (const float*)d_in[2];
  const float* Wih0  = (const float*)d_in[3];
  const float* Whh0  = (const float*)d_in[4];
  const float* bih0  = (const float*)d_in[5];
  const float* bhh0  = (const float*)d_in[6];
  const float* Wih1  = (const float*)d_in[7];
  const float* Whh1  = (const float*)d_in[8];
  const float* bih1  = (const float*)d_in[9];
  const float* bhh1  = (const float*)d_in[10];
  const float* Wih2  = (const float*)d_in[11];
  const float* Whh2  = (const float*)d_in[12];
  const float* bih2  = (const float*)d_in[13];
  const float* bhh2  = (const float*)d_in[14];
  const float* Wout1 = (const float*)d_in[15];
  const float* bout1 = (const float*)d_in[16];
  const float* ln_g  = (const float*)d_in[17];
  const float* ln_b  = (const float*)d_in[18];
  const float* Wout2 = (const float*)d_in[19];
  const float* bout2 = (const float*)d_in[20];
  float* out = (float*)d_out;
  char* ws = (char*)d_ws;

  // ws layout (bytes)
  const size_t ACT0_OFF = 0;                      // 8,192,000  (64000*64*2)
  const size_t YA_OFF   = 8192000;                // 32,768,000 (64000*256*2)
  const size_t YB_OFF   = 40960000;               // 32,768,000
  const size_t WT_OFF   = 73728000;               // 3,014,656  (1,507,328 bf16)

  ushort_t* act0 = (ushort_t*)(ws + ACT0_OFF);
  ushort_t* Ya   = (ushort_t*)(ws + YA_OFF);
  ushort_t* Yb   = (ushort_t*)(ws + YB_OFF);
  ushort_t* WT   = (ushort_t*)(ws + WT_OFF);
  ushort_t* aggb = (ushort_t*)(ws + 0);           // reuses act0 region (dead by then)

  ushort_t* WT_ih0 = WT + 0;
  ushort_t* WT_ih1 = WT + 65536;
  ushort_t* WT_ih2 = WT + 327680;
  ushort_t* WT_hh0 = WT + 589824;
  ushort_t* WT_hh1 = WT + 720896;
  ushort_t* WT_hh2 = WT + 851968;
  ushort_t* W1T    = WT + 983040;
  ushort_t* W2T    = WT + 1376256;

  k_pre<<<16736, 256, 0, stream>>>(Wih0, Wih1, Wih2, Whh0, Whh1, Whh2,
                                   Wout1, Wout2, WT, imu, W_in, b_in, act0);

  const dim3 sg(80, 2);
  k_scan<0, 64><<<sg, 512, 0, stream>>>(act0, WT_ih0, WT_hh0, bih0, bhh0, Ya, aggb);
  k_scan<0, 256><<<sg, 512, 0, stream>>>(Ya, WT_ih1, WT_hh1, bih1, bhh1, Yb, aggb);
  k_scan<1, 256><<<sg, 512, 0, stream>>>(Yb, WT_ih2, WT_hh2, bih2, bhh2, Ya, aggb);

  k_head<<<20, 512, 0, stream>>>(aggb, W1T, bout1, ln_g, ln_b, W2T, bout2, out);
}

// Round 11
// 358.025 us; speedup vs baseline: 1.1058x; 1.0063x over previous
//
#include <hip/hip_runtime.h>
#include <stdint.h>

// ---------------------------------------------------------------------------
// TimeAwareIMULSTMEncoder on MI355X (gfx950) — round 16 (polish)
// Round 15 verified: wide Y flush cut k_scan 115->92 us (WRITE segments full
// width, Y L2-resident for next layer). Scan is at its latency floor for this
// decomposition: the h(t)->h(t+1) block-wide barrier chain is irreducible
// (Whh dense -> every gate needs all 128 h-cols), 192 weight regs pin
// occupancy at 2 waves/SIMD (4/SIMD spills: round 12), dual-stream variants
// lose to grid-halving (round 11) or registers (round 12).
// This round: non-scan polish only.
//  * k_pre inproj vectorized: 4 outputs/thread, one uint2 store (was 1
//    scalar 2-B store/thread), x row loaded once -> 1.02M threads.
//  * scans/head byte-identical to round 15.
// ---------------------------------------------------------------------------

typedef unsigned short ushort_t;
typedef short short8 __attribute__((ext_vector_type(8)));     // 8 bf16 (4 VGPRs)
typedef float float4v __attribute__((ext_vector_type(4)));    // MFMA acc

#define DEV_INLINE __device__ __forceinline__

DEV_INLINE ushort_t f2bf(float f) {                 // RNE f32 -> bf16 bits
  union { float f; unsigned u; } v; v.f = f;
  unsigned r = v.u + 0x7fffu + ((v.u >> 16) & 1u);
  return (ushort_t)(r >> 16);
}
DEV_INLINE float sigmoidf_(float x) {
  return __builtin_amdgcn_rcpf(1.0f + __expf(-x));
}
DEV_INLINE float tanhf_(float x) {                  // 1 - 2/(1+e^{2x}); safe at +-inf
  return 1.0f - 2.0f * __builtin_amdgcn_rcpf(1.0f + __expf(2.0f * x));
}

// LDS-only barrier: ds-op completion + rendezvous, no vmcnt drain.
DEV_INLINE void lds_barrier() {
  asm volatile("s_waitcnt lgkmcnt(0)\n\ts_barrier" ::: "memory");
}

// async global->LDS, 16B per lane; dst must be wave-uniform base + lane*16.
DEV_INLINE void gload16(const ushort_t* g, ushort_t* l) {
  __builtin_amdgcn_global_load_lds(
      (const __attribute__((address_space(1))) unsigned int*)g,
      (__attribute__((address_space(3))) unsigned int*)l, 16, 0, 0);
}

// ----------------- fused weight prep + input projection ---------------------
// blocks 0..735: tiled transpose of all weights to bf16 n-major.
// blocks 736..4735: input projection imu -> act0, 4 outputs/thread (uint2).
__global__ __launch_bounds__(256) void k_pre(
    const float* __restrict__ Wih0, const float* __restrict__ Wih1,
    const float* __restrict__ Wih2, const float* __restrict__ Whh0,
    const float* __restrict__ Whh1, const float* __restrict__ Whh2,
    const float* __restrict__ Wout1, const float* __restrict__ Wout2,
    ushort_t* __restrict__ WT,
    const float* __restrict__ imu, const float* __restrict__ W_in,
    const float* __restrict__ b_in, ushort_t* __restrict__ act0)
{
  __shared__ float T[32][65];
  const int tid = threadIdx.x;

  if (blockIdx.x >= 736) {              // ---- input projection ----
    int idx = (blockIdx.x - 736) * 256 + tid;   // 1,024,000 = 64000*16 exactly
    int jq = (idx & 15) * 4, r = idx >> 4;
    int l = r % 50;
    const float* x = imu + (size_t)r * 6;
    float xl[6];
#pragma unroll
    for (int d = 0; d < 6; d++) xl[d] = x[d];
    float tcoef = l * (1.0f / 49.0f);
    ushort_t pk[4];
#pragma unroll
    for (int u = 0; u < 4; u++) {
      int j = jq + u;
      float acc = b_in[j];
#pragma unroll
      for (int d = 0; d < 6; d++) acc += xl[d] * W_in[d * 64 + j];
      acc += tcoef * W_in[6 * 64 + j] + W_in[7 * 64 + j];   // t, rate=1
      pk[u] = f2bf(fmaxf(acc, 0.0f));
    }
    *(uint2*)(act0 + (size_t)r * 64 + jq) = *(uint2*)pk;
    return;
  }

  // ---- weight prep (tiled transpose) ----
  const int b = blockIdx.x;
  const float* S; int Kd, C; size_t dstBase; int kt, nt;
  if (b < 32) {
    int rel = b; int d = (rel >> 3) / 2; kt = (rel >> 3) & 1; nt = rel & 7;
    S = Wih0 + (size_t)d * 64 * 512; C = 512; Kd = 64;
    dstBase = 0 + (size_t)d * 512 * 64;
  } else if (b < 160) {
    int rel = b - 32; int d = (rel >> 3) / 8; kt = (rel >> 3) & 7; nt = rel & 7;
    S = Wih1 + (size_t)d * 256 * 512; C = 512; Kd = 256;
    dstBase = 65536 + (size_t)d * 512 * 256;
  } else if (b < 288) {
    int rel = b - 160; int d = (rel >> 3) / 8; kt = (rel >> 3) & 7; nt = rel & 7;
    S = Wih2 + (size_t)d * 256 * 512; C = 512; Kd = 256;
    dstBase = 327680 + (size_t)d * 512 * 256;
  } else if (b < 352) {
    int rel = b - 288; int d = (rel >> 3) / 4; kt = (rel >> 3) & 3; nt = rel & 7;
    S = Whh0 + (size_t)d * 128 * 512; C = 512; Kd = 128;
    dstBase = 589824 + (size_t)d * 512 * 128;
  } else if (b < 416) {
    int rel = b - 352; int d = (rel >> 3) / 4; kt = (rel >> 3) & 3; nt = rel & 7;
    S = Whh1 + (size_t)d * 128 * 512; C = 512; Kd = 128;
    dstBase = 720896 + (size_t)d * 512 * 128;
  } else if (b < 480) {
    int rel = b - 416; int d = (rel >> 3) / 4; kt = (rel >> 3) & 3; nt = rel & 7;
    S = Whh2 + (size_t)d * 128 * 512; C = 512; Kd = 128;
    dstBase = 851968 + (size_t)d * 512 * 128;
  } else if (b < 672) {
    int rel = b - 480; kt = rel >> 3; nt = rel & 7;
    S = Wout1; C = 512; Kd = 768; dstBase = 983040;
  } else {
    int rel = b - 672; kt = rel >> 2; nt = rel & 3;
    S = Wout2; C = 256; Kd = 512; dstBase = 1376256;
  }
  const int k0 = kt * 32, n0 = nt * 64;
  {
    int kr = tid >> 6;                // 0..3
    int n  = tid & 63;
#pragma unroll
    for (int i = 0; i < 8; i++)
      T[i * 4 + kr][n] = S[(size_t)(k0 + i * 4 + kr) * C + n0 + n];
  }
  __syncthreads();
  {
    int n = tid >> 2;                 // 0..63
    int ko = (tid & 3) * 8;           // 0,8,16,24
    ushort_t pk[8];
#pragma unroll
    for (int j = 0; j < 8; j++) pk[j] = f2bf(T[ko + j][n]);
    *(uint4*)(WT + dstBase + (size_t)(n0 + n) * Kd + k0 + ko) = *(uint4*)pk;
  }
}

// --------------------------- fused LSTM scan (round 15, unchanged) ----------
// One block = 16 seqs of one direction, 512 thr / 8 waves, gate-quad waves.
// Wave w: gates 0..3 for hcols w*16+cl. Per step:
//   wide-flush h(t-1) from hbuf[cur] (1 dwordx2/thread, MODE 0);
//   read Ax (K/32 b128 from Xs) + Ah (4 b128 from hbuf); prefetch next X
//   rows to VGPRs; 4 gate accs = bias + x@Wih + h@Whh (all-reg weights);
//   in-register LSTM pointwise (lane holds i,f,g,o of 4 cells); write h to
//   hbuf; land X prefetch; ONE LDS-only barrier (no vmcnt drain).
// MODE 0: wide Y flush. MODE 1: fused mean/max/final aggregation.
template <int MODE, int K>
__global__ __launch_bounds__(512, 2) void k_scan(
    const ushort_t* __restrict__ X,     // [seq*50+t][K] bf16
    const ushort_t* __restrict__ WihT,  // [2][512][K] bf16 n-major
    const ushort_t* __restrict__ WhhT,  // [2][512][128] bf16 n-major
    const float* __restrict__ bih, const float* __restrict__ bhh, // [2][512]
    ushort_t* __restrict__ Y,           // [64000][256] bf16 (MODE 0)
    ushort_t* __restrict__ aggb)        // [1280][768] bf16 (MODE 1)
{
  constexpr int NKT = K / 32;           // 2 (K=64) or 8 (K=256)
  constexpr int XST2 = K + 8;           // Xs row stride (ushorts)
  const int dir = blockIdx.y;
  const int s0 = blockIdx.x * 16;
  const int tid = threadIdx.x;
  const int wave = tid >> 6, lane = tid & 63;   // wave = hcol group 0..7
  const int cl = lane & 15, quad = lane >> 4;
  const int hcol = wave * 16 + cl;              // 0..127
  const int frow = tid >> 5, fcol = (tid & 31) * 4;  // wide-flush mapping

  __shared__ __align__(16) ushort_t hbuf[2][16][136];   //  8.5 KiB
  __shared__ __align__(16) ushort_t Xs[2][16 * XST2];   // 16.5 KiB (K=256)

  // register/AGPR-resident weights: 4 gates x 16 hcols for this wave
  short8 Bx[4][NKT], Bh[4][4];
  {
    const ushort_t* Wx = WihT + (size_t)dir * (512 * K);
    const ushort_t* Wd = WhhT + (size_t)dir * (512 * 128);
#pragma unroll
    for (int g = 0; g < 4; g++) {
#pragma unroll
      for (int kt = 0; kt < NKT; kt++)
        Bx[g][kt] = *(const short8*)(Wx + (size_t)(g * 128 + hcol) * K + kt * 32 + quad * 8);
#pragma unroll
      for (int kt = 0; kt < 4; kt++)
        Bh[g][kt] = *(const short8*)(Wd + (size_t)(g * 128 + hcol) * 128 + kt * 32 + quad * 8);
    }
  }
  float bias[4];
#pragma unroll
  for (int g = 0; g < 4; g++) {
    const int gc = dir * 512 + g * 128 + hcol;
    bias[g] = bih[gc] + bhh[gc];
  }

  float cst[4] = {0.f, 0.f, 0.f, 0.f};
  float sum[4] = {0.f, 0.f, 0.f, 0.f};
  float mx[4]  = {-3.0e38f, -3.0e38f, -3.0e38f, -3.0e38f};

  for (int i = tid; i < 16 * 136; i += 512) ((ushort_t*)hbuf)[i] = 0;

  {  // stage X(step 0): 16 rows; wave w stages rows 2w, 2w+1 (8B/lane)
    const int tt = dir ? 49 : 0;
    if (K == 256) {
      uint2 v0 = *(const uint2*)(X + ((size_t)(s0 + wave * 2 + 0) * 50 + tt) * K + lane * 4);
      uint2 v1 = *(const uint2*)(X + ((size_t)(s0 + wave * 2 + 1) * 50 + tt) * K + lane * 4);
      *(uint2*)(&Xs[0][(wave * 2 + 0) * XST2 + lane * 4]) = v0;
      *(uint2*)(&Xs[0][(wave * 2 + 1) * XST2 + lane * 4]) = v1;
    } else if (lane < 32) {
      uint2 v0 = *(const uint2*)(X + ((size_t)(s0 + wave * 2 + (lane >> 4)) * 50 + tt) * K + (lane & 15) * 4);
      *(uint2*)(&Xs[0][(wave * 2 + (lane >> 4)) * XST2 + (lane & 15) * 4]) = v0;
    }
  }
  __syncthreads();                      // hbuf zero + Xs[0] visible (full sync ok once)

  for (int step = 0; step < 50; step++) {
    const int t = dir ? (49 - step) : step;
    const int cur = step & 1;

    // wide flush of h(t-1) from hbuf[cur] (Y stays L2-resident for next layer)
    if (MODE == 0 && step > 0) {
      const int tp = dir ? (t + 1) : (t - 1);
      uint2 hv = *(const uint2*)(&hbuf[cur][frow][fcol]);
      *(uint2*)(Y + ((size_t)(s0 + frow) * 50 + tp) * 256 + dir * 128 + fcol) = hv;
    }

    // A fragments (shared across the wave's 4 gates)
    short8 Ax[NKT], Ah[4];
#pragma unroll
    for (int kt = 0; kt < NKT; kt++)
      Ax[kt] = *(const short8*)(&Xs[cur][cl * XST2 + kt * 32 + quad * 8]);
#pragma unroll
    for (int kt = 0; kt < 4; kt++)
      Ah[kt] = *(const short8*)(&hbuf[cur][cl][kt * 32 + quad * 8]);

    // prefetch next step's X rows into VGPRs (landed after pointwise)
    uint2 xr0 = {0u, 0u}, xr1 = {0u, 0u};
    if (step < 49) {
      const int t1 = dir ? (t - 1) : (t + 1);
      if (K == 256) {
        xr0 = *(const uint2*)(X + ((size_t)(s0 + wave * 2 + 0) * 50 + t1) * K + lane * 4);
        xr1 = *(const uint2*)(X + ((size_t)(s0 + wave * 2 + 1) * 50 + t1) * K + lane * 4);
      } else if (lane < 32) {
        xr0 = *(const uint2*)(X + ((size_t)(s0 + wave * 2 + (lane >> 4)) * 50 + t1) * K + (lane & 15) * 4);
      }
    }

    // 4 gate accumulators: bias + x@Wih + h@Whh
    float4v acc[4];
#pragma unroll
    for (int g = 0; g < 4; g++) acc[g] = float4v{bias[g], bias[g], bias[g], bias[g]};
#pragma unroll
    for (int kt = 0; kt < NKT; kt++)
#pragma unroll
      for (int g = 0; g < 4; g++)
        acc[g] = __builtin_amdgcn_mfma_f32_16x16x32_bf16(Ax[kt], Bx[g][kt], acc[g], 0, 0, 0);
#pragma unroll
    for (int kt = 0; kt < 4; kt++)
#pragma unroll
      for (int g = 0; g < 4; g++)
        acc[g] = __builtin_amdgcn_mfma_f32_16x16x32_bf16(Ah[kt], Bh[g][kt], acc[g], 0, 0, 0);

    // in-register pointwise: lane holds i,f,g,o of cells (quad*4+r, hcol)
#pragma unroll
    for (int r = 0; r < 4; r++) {
      float ii = sigmoidf_(acc[0][r]);
      float ff = sigmoidf_(acc[1][r]);
      float gc = tanhf_(acc[2][r]);
      float oo = sigmoidf_(acc[3][r]);
      float c2 = ff * cst[r] + ii * gc;
      cst[r] = c2;
      float h = oo * tanhf_(c2);
      hbuf[cur ^ 1][quad * 4 + r][hcol] = f2bf(h);
      if (MODE == 1) {
        sum[r] += h;
        mx[r] = fmaxf(mx[r], h);
        if (step == 49) {               // h here is h_n of this dir
          const size_t seq = s0 + quad * 4 + r;
          const int cc = dir * 128 + hcol;
          aggb[seq * 768 + cc]       = f2bf(sum[r] * (1.0f / 50.0f));
          aggb[seq * 768 + 256 + cc] = f2bf(mx[r]);
          aggb[seq * 768 + 512 + cc] = f2bf(h);
        }
      }
    }

    // land X prefetch into the other buffer (dep-based vmcnt wait only here)
    if (step < 49) {
      if (K == 256) {
        *(uint2*)(&Xs[cur ^ 1][(wave * 2 + 0) * XST2 + lane * 4]) = xr0;
        *(uint2*)(&Xs[cur ^ 1][(wave * 2 + 1) * XST2 + lane * 4]) = xr1;
      } else if (lane < 32) {
        *(uint2*)(&Xs[cur ^ 1][(wave * 2 + (lane >> 4)) * XST2 + (lane & 15) * 4]) = xr0;
      }
    }
    lds_barrier();                      // h + Xs visible; vmcnt NOT drained
  }

  if (MODE == 0) {                      // flush h(49) (step 49 wrote hbuf[0])
    const int tl = dir ? 0 : 49;
    uint2 hv = *(const uint2*)(&hbuf[0][frow][fcol]);
    *(uint2*)(Y + ((size_t)(s0 + frow) * 50 + tl) * 256 + dir * 128 + fcol) = hv;
  }
}

// --------------------------- fused head -------------------------------------
__global__ __launch_bounds__(512, 1) void k_head(
    const ushort_t* __restrict__ aggb,  // [1280][768] bf16
    const ushort_t* __restrict__ W1T,   // [512][768] bf16
    const float* __restrict__ b1, const float* __restrict__ ln_g,
    const float* __restrict__ ln_b,
    const ushort_t* __restrict__ W2T,   // [256][512] bf16
    const float* __restrict__ b2, float* __restrict__ out) // [1280][256]
{
  __shared__ __align__(16) char smem[78336];
  ushort_t* AsB = (ushort_t*)smem;            // [2][64*32]   (8 KiB)
  ushort_t* BsB = (ushort_t*)(smem + 8192);   // [2][512*32]  (64 KiB)
  ushort_t* hn  = (ushort_t*)smem;            // [64][520] aliased (66.6 KiB)
  float* partS  = (float*)(smem + 73728);     // [64][8]
  float* partQ  = partS + 512;                // [64][8]
  float* muS    = partQ + 512;                // [64]
  float* rsS    = muS + 64;                   // [64]

  const int m0 = blockIdx.x * 64;
  const int tid = threadIdx.x;
  const int wave = tid >> 6, lane = tid & 63;
  const int cl = lane & 15, quad = lane >> 4;
  const int srow = lane >> 2, scol = (lane & 3) * 8;

  float4v acc1[4][4];
#pragma unroll
  for (int i = 0; i < 4; i++)
#pragma unroll
    for (int v = 0; v < 4; v++) acc1[i][v] = float4v{0.f, 0.f, 0.f, 0.f};

#define STAGE1(buf, kb)                                                       \
  {                                                                           \
    if (wave < 4)                                                             \
      gload16(aggb + (size_t)(m0 + wave * 16 + srow) * 768 + (kb) + scol,     \
              AsB + (buf) * 2048 + wave * 16 * 32 + lane * 8);                \
    _Pragma("unroll")                                                         \
    for (int j = 0; j < 4; j++)                                               \
      gload16(W1T + (size_t)(wave * 64 + j * 16 + srow) * 768 + (kb) + scol,  \
              BsB + (buf) * 16384 + (wave * 64 + j * 16) * 32 + lane * 8);    \
  }

  STAGE1(0, 0)
  for (int kb = 0; kb < 768; kb += 32) {
    const int cur = (kb >> 5) & 1;
    __syncthreads();
    if (kb + 32 < 768) STAGE1(cur ^ 1, kb + 32)
    short8 Af[4], Bf[4];
#pragma unroll
    for (int i = 0; i < 4; i++)
      Af[i] = *(const short8*)(AsB + cur * 2048 + (i * 16 + cl) * 32 + quad * 8);
#pragma unroll
    for (int v = 0; v < 4; v++)
      Bf[v] = *(const short8*)(BsB + cur * 16384 + (wave * 64 + v * 16 + cl) * 32 + quad * 8);
#pragma unroll
    for (int i = 0; i < 4; i++)
#pragma unroll
      for (int v = 0; v < 4; v++)
        acc1[i][v] = __builtin_amdgcn_mfma_f32_16x16x32_bf16(Af[i], Bf[v], acc1[i][v], 0, 0, 0);
  }
#undef STAGE1
  __syncthreads();          // all waves done with AsB/BsB (hn aliases them)

  float bcol[4], lg[4], lb[4];
#pragma unroll
  for (int v = 0; v < 4; v++) {
    int col = wave * 64 + v * 16 + cl;
    bcol[v] = b1[col]; lg[v] = ln_g[col]; lb[v] = ln_b[col];
  }

#pragma unroll
  for (int i = 0; i < 4; i++) {
#pragma unroll
    for (int r = 0; r < 4; r++) {
      float s = 0.f, q = 0.f;
#pragma unroll
      for (int v = 0; v < 4; v++) {
        float x = acc1[i][v][r] + bcol[v];
        s += x; q += x * x;
      }
#pragma unroll
      for (int m = 1; m <= 8; m <<= 1) {
        s += __shfl_xor(s, m);
        q += __shfl_xor(q, m);
      }
      if (cl == 0) {
        int row = i * 16 + quad * 4 + r;
        partS[row * 8 + wave] = s;
        partQ[row * 8 + wave] = q;
      }
    }
  }
  __syncthreads();
  if (tid < 64) {
    float s = 0.f, q = 0.f;
#pragma unroll
    for (int w = 0; w < 8; w++) { s += partS[tid * 8 + w]; q += partQ[tid * 8 + w]; }
    float mu = s * (1.0f / 512.0f);
    float var = q * (1.0f / 512.0f) - mu * mu;
    muS[tid] = mu;
    rsS[tid] = rsqrtf(var + 1e-5f);
  }
  __syncthreads();

#pragma unroll
  for (int i = 0; i < 4; i++) {
#pragma unroll
    for (int r = 0; r < 4; r++) {
      int row = i * 16 + quad * 4 + r;
      float mu = muS[row], rs = rsS[row];
#pragma unroll
      for (int v = 0; v < 4; v++) {
        int col = wave * 64 + v * 16 + cl;
        float x = acc1[i][v][r] + bcol[v];
        float y = (x - mu) * rs * lg[v] + lb[v];
        hn[row * 520 + col] = f2bf(fmaxf(y, 0.0f));
      }
    }
  }
  __syncthreads();

  float4v acc2[4][2];
#pragma unroll
  for (int i = 0; i < 4; i++)
#pragma unroll
    for (int u = 0; u < 2; u++) acc2[i][u] = float4v{0.f, 0.f, 0.f, 0.f};
  for (int kt = 0; kt < 16; kt++) {
    short8 Af2[4], Bf2[2];
#pragma unroll
    for (int u = 0; u < 2; u++)
      Bf2[u] = *(const short8*)(W2T + (size_t)(wave * 32 + u * 16 + cl) * 512 + kt * 32 + quad * 8);
#pragma unroll
    for (int i = 0; i < 4; i++)
      Af2[i] = *(const short8*)(hn + (i * 16 + cl) * 520 + kt * 32 + quad * 8);
#pragma unroll
    for (int i = 0; i < 4; i++)
#pragma unroll
      for (int u = 0; u < 2; u++)
        acc2[i][u] = __builtin_amdgcn_mfma_f32_16x16x32_bf16(Af2[i], Bf2[u], acc2[i][u], 0, 0, 0);
  }
#pragma unroll
  for (int u = 0; u < 2; u++) {
    int col = wave * 32 + u * 16 + cl;
    float bb = b2[col];
#pragma unroll
    for (int i = 0; i < 4; i++)
#pragma unroll
      for (int r = 0; r < 4; r++)
        out[(size_t)(m0 + i * 16 + quad * 4 + r) * 256 + col] = acc2[i][u][r] + bb;
  }
}

// --------------------------- launcher --------------------------------------
extern "C" void kernel_launch(void* const* d_in, const int* in_sizes, int n_in,
                              void* d_out, int out_size, void* d_ws, size_t ws_size,
                              hipStream_t stream)
{
  (void)in_sizes; (void)n_in; (void)out_size; (void)ws_size;
  const float* imu   = (const float*)d_in[0];
  const float* W_in  = (const float*)d_in[1];
  const float* b_in  = (const float*)d_in[2];
  const float* Wih0  = (const float*)d_in[3];
  const float* Whh0  = (const float*)d_in[4];
  const float* bih0  = (const float*)d_in[5];
  const float* bhh0  = (const float*)d_in[6];
  const float* Wih1  = (const float*)d_in[7];
  const float* Whh1  = (const float*)d_in[8];
  const float* bih1  = (const float*)d_in[9];
  const float* bhh1  = (const float*)d_in[10];
  const float* Wih2  = (const float*)d_in[11];
  const float* Whh2  = (const float*)d_in[12];
  const float* bih2  = (const float*)d_in[13];
  const float* bhh2  = (const float*)d_in[14];
  const float* Wout1 = (const float*)d_in[15];
  const float* bout1 = (const float*)d_in[16];
  const float* ln_g  = (const float*)d_in[17];
  const float* ln_b  = (const float*)d_in[18];
  const float* Wout2 = (const float*)d_in[19];
  const float* bout2 = (const float*)d_in[20];
  float* out = (float*)d_out;
  char* ws = (char*)d_ws;

  // ws layout (bytes)
  const size_t ACT0_OFF = 0;                      // 8,192,000  (64000*64*2)
  const size_t YA_OFF   = 8192000;                // 32,768,000 (64000*256*2)
  const size_t YB_OFF   = 40960000;               // 32,768,000
  const size_t WT_OFF   = 73728000;               // 3,014,656  (1,507,328 bf16)

  ushort_t* act0 = (ushort_t*)(ws + ACT0_OFF);
  ushort_t* Ya   = (ushort_t*)(ws + YA_OFF);
  ushort_t* Yb   = (ushort_t*)(ws + YB_OFF);
  ushort_t* WT   = (ushort_t*)(ws + WT_OFF);
  ushort_t* aggb = (ushort_t*)(ws + 0);           // reuses act0 region (dead by then)

  ushort_t* WT_ih0 = WT + 0;
  ushort_t* WT_ih1 = WT + 65536;
  ushort_t* WT_ih2 = WT + 327680;
  ushort_t* WT_hh0 = WT + 589824;
  ushort_t* WT_hh1 = WT + 720896;
  ushort_t* WT_hh2 = WT + 851968;
  ushort_t* W1T    = WT + 983040;
  ushort_t* W2T    = WT + 1376256;

  k_pre<<<4736, 256, 0, stream>>>(Wih0, Wih1, Wih2, Whh0, Whh1, Whh2,
                                  Wout1, Wout2, WT, imu, W_in, b_in, act0);

  const dim3 sg(80, 2);
  k_scan<0, 64><<<sg, 512, 0, stream>>>(act0, WT_ih0, WT_hh0, bih0, bhh0, Ya, aggb);
  k_scan<0, 256><<<sg, 512, 0, stream>>>(Ya, WT_ih1, WT_hh1, bih1, bhh1, Yb, aggb);
  k_scan<1, 256><<<sg, 512, 0, stream>>>(Yb, WT_ih2, WT_hh2, bih2, bhh2, Ya, aggb);

  k_head<<<20, 512, 0, stream>>>(aggb, W1T, bout1, ln_g, ln_b, W2T, bout2, out);
}